// Round 18
// baseline (1590.101 us; speedup 1.0000x reference)
//
#include <hip/hip_runtime.h>

// ---------------------------------------------------------------------------
// VQ-VAE encoder: 4x [conv k=4 s=2 p=1 + ReLU] then nearest-codebook lookup.
// Round 18: BARRIER-FREE streaming VQ. The cl LDS tile + 512 barriers/block
// existed only to share codebook data that the caches already share (each
// block's 2MB quarter is L2-resident; each 1KB cbT row is L1-hot across the
// block's 4 waves). Threads now read cbT directly per kk (8 unique 16B
// addrs/wave, qg-duplicates hardware-merged); zt stays in LDS. Main loop has
// ZERO barriers -> waves free-run, loads schedule arbitrarily ahead.
// Same k-ascending fma chain on bit-identical values -> same argmin.
// conv path unchanged from round-15/17 measured best.
// ---------------------------------------------------------------------------

#define THREADS 256

// ---- old 4co x 8wo template (used only for conv1, CIN=3) ----
template<int CINR, int KC, int CTOT, bool PARTIAL, int WROWP>
__global__ __launch_bounds__(THREADS)
void conv_tiled_kernel(const float* __restrict__ x, const float* __restrict__ w,
                       const float* __restrict__ bias, float* __restrict__ y,
                       int B, int Cout, int Hin, int Win,
                       int nCt, int nHt, int nWt) {
    constexpr int TH = 8, TW = 16, TC = 64;
    constexpr int XR = 2 * TH + 2;
    constexpr int XC = 2 * TW + 2;
    constexpr int ROWP = 36;
    constexpr int XTOT = KC * XR * ROWP;
    constexpr int WROW16 = KC * 16;
    constexpr int WTOT = TC * WROW16;

    __shared__ float xs[KC][XR][ROWP];
    __shared__ float ws_f[TC * WROWP];

    const int Ho = Hin >> 1, Wo = Win >> 1;

    int id = blockIdx.x;
    const int wt = id % nWt; id /= nWt;
    const int ht = id % nHt; id /= nHt;
    const int ct = id % nCt; const int b = id / nCt;
    const int cib = blockIdx.y * CINR;

    const int oh0 = ht * TH, ow0 = wt * TW, co0 = ct * TC;
    const int h0 = 2 * oh0 - 1;
    const int w0 = 2 * ow0 - 1;

    const int tid  = threadIdx.x;
    const int co_l = (tid >> 4) * 4;
    const int sp   = tid & 15;
    const int lho  = sp >> 1;
    const int lwo  = (sp & 1) * 8;

    float acc[4][8];
    #pragma unroll
    for (int co = 0; co < 4; ++co) {
        const float bv = PARTIAL ? 0.0f : bias[co0 + co_l + co];
        #pragma unroll
        for (int j = 0; j < 8; ++j) acc[co][j] = bv;
    }

    float* __restrict__ xs_fl = &xs[0][0][0];

    for (int cc = 0; cc < CINR / KC; ++cc) {
        const int ci0 = cc * KC;

        for (int j = tid; j < XTOT; j += THREADS) {
            const int ci = j / (XR * ROWP);
            const int rr = (j - ci * (XR * ROWP)) / ROWP;
            const int c  = j % ROWP;
            const int hi = h0 + rr;
            const int wi = w0 + c;
            float v = 0.0f;
            if (c < XC && (unsigned)hi < (unsigned)Hin && (unsigned)wi < (unsigned)Win)
                v = x[((b * CTOT + cib + ci0 + ci) * Hin + hi) * Win + wi];
            xs_fl[j] = v;
        }
        for (int j = tid; j < WTOT; j += THREADS) {
            const int co  = j / WROW16;
            const int rem = j - co * WROW16;
            ws_f[co * WROWP + rem] = w[((co0 + co) * CTOT + cib + ci0) * 16 + rem];
        }
        __syncthreads();

        #pragma unroll 1
        for (int ci = 0; ci < KC; ++ci) {
            #pragma unroll
            for (int kh = 0; kh < 4; ++kh) {
                const float* __restrict__ xr = &xs[ci][2 * lho + kh][2 * lwo];
                const float4 a0 = *(const float4*)(xr + 0);
                const float4 a1 = *(const float4*)(xr + 4);
                const float4 a2 = *(const float4*)(xr + 8);
                const float4 a3 = *(const float4*)(xr + 12);
                const float4 a4 = *(const float4*)(xr + 16);
                const float xf[20] = {a0.x, a0.y, a0.z, a0.w,
                                      a1.x, a1.y, a1.z, a1.w,
                                      a2.x, a2.y, a2.z, a2.w,
                                      a3.x, a3.y, a3.z, a3.w,
                                      a4.x, a4.y, a4.z, a4.w};
                #pragma unroll
                for (int co = 0; co < 4; ++co) {
                    const float4 wv =
                        *(const float4*)&ws_f[(co_l + co) * WROWP + ci * 16 + kh * 4];
                    #pragma unroll
                    for (int j = 0; j < 8; ++j) {
                        acc[co][j] = fmaf(xf[2 * j + 0], wv.x, acc[co][j]);
                        acc[co][j] = fmaf(xf[2 * j + 1], wv.y, acc[co][j]);
                        acc[co][j] = fmaf(xf[2 * j + 2], wv.z, acc[co][j]);
                        acc[co][j] = fmaf(xf[2 * j + 3], wv.w, acc[co][j]);
                    }
                }
            }
        }
        __syncthreads();
    }

    float* __restrict__ yb = y;
    if (PARTIAL) yb += (size_t)blockIdx.y * (size_t)(B * Cout * Ho * Wo);
    #pragma unroll
    for (int co = 0; co < 4; ++co) {
        float* __restrict__ yp =
            &yb[((b * Cout + co0 + co_l + co) * Ho + oh0 + lho) * Wo + ow0 + lwo];
        float4 r0, r1;
        if (PARTIAL) {
            r0 = make_float4(acc[co][0], acc[co][1], acc[co][2], acc[co][3]);
            r1 = make_float4(acc[co][4], acc[co][5], acc[co][6], acc[co][7]);
        } else {
            r0 = make_float4(fmaxf(acc[co][0], 0.0f), fmaxf(acc[co][1], 0.0f),
                             fmaxf(acc[co][2], 0.0f), fmaxf(acc[co][3], 0.0f));
            r1 = make_float4(fmaxf(acc[co][4], 0.0f), fmaxf(acc[co][5], 0.0f),
                             fmaxf(acc[co][6], 0.0f), fmaxf(acc[co][7], 0.0f));
        }
        *(float4*)yp       = r0;
        *(float4*)(yp + 4) = r1;
    }
}

// ---- 8co x 8wo template, 128-co block tile, T14 pipeline, deint-xs ----
template<int CINR, int KC, int CTOT, bool PARTIAL>
__global__ __launch_bounds__(THREADS)
void conv_tiled8_kernel(const float* __restrict__ x, const float* __restrict__ w,
                        const float* __restrict__ bias, float* __restrict__ y,
                        int B, int Cout, int Hin, int Win,
                        int nCt, int nHt, int nWt) {
    constexpr int TH = 8, TW = 16, TC = 128;
    constexpr int XR = 2 * TH + 2;      // 18
    constexpr int XC = 2 * TW + 2;      // 34
    constexpr int ROWP = 36;
    constexpr int XTOT = KC * XR * ROWP;            // 1296 @ KC=2
    constexpr int NXS  = (XTOT + THREADS - 1) / THREADS;  // 6
    constexpr int WROW16 = KC * 16;     // 32
    constexpr int WROWP  = KC * 16 + 4; // 36
    constexpr int NWS  = TC * WROW16 / THREADS;     // 16
    constexpr int NCC  = CINR / KC;

    __shared__ float xs[KC][XR][ROWP];  // 5.1 KB @ KC=2 (rows deinterleaved)
    __shared__ float ws_f[TC * WROWP];  // 18.4 KB @ KC=2

    const int Ho = Hin >> 1, Wo = Win >> 1;

    int id = blockIdx.x;
    const int wt = id % nWt; id /= nWt;
    const int ht = id % nHt; id /= nHt;
    const int ct = id % nCt; const int b = id / nCt;
    const int cib = blockIdx.y * CINR;

    const int oh0 = ht * TH, ow0 = wt * TW, co0 = ct * TC;
    const int h0 = 2 * oh0 - 1;
    const int w0 = 2 * ow0 - 1;

    const int tid = threadIdx.x;
    const int cog = tid >> 4;           // 16 groups x 8 co
    const int sp  = tid & 15;
    const int lho = sp >> 1;            // 0..7
    const int lwo = (sp & 1) * 8;       // 0 or 8

    float acc[8][8];
    #pragma unroll
    for (int cl = 0; cl < 8; ++cl) {
        const float bv = PARTIAL ? 0.0f : bias[co0 + cog * 8 + cl];
        #pragma unroll
        for (int j = 0; j < 8; ++j) acc[cl][j] = bv;
    }

    float* __restrict__ xs_fl = &xs[0][0][0];

    // ---- cc-invariant staging descriptors (incl. deinterleaved LDS idx) ----
    int  xoff[NXS];
    int  xlds[NXS];
    bool xok[NXS];
    #pragma unroll
    for (int s = 0; s < NXS; ++s) {
        const int j  = tid + s * THREADS;
        const int ci = j / (XR * ROWP);
        const int rr = (j - ci * (XR * ROWP)) / ROWP;
        const int c  = j % ROWP;
        const int hi = h0 + rr;
        const int wi = w0 + c;
        const bool ok = (j < XTOT) && (c < XC) &&
                        ((unsigned)hi < (unsigned)Hin) &&
                        ((unsigned)wi < (unsigned)Win);
        xok[s]  = ok;
        xoff[s] = ok ? (((b * CTOT + cib + ci) * Hin + hi) * Win + wi) : 0;
        const int rp = ((rr & 1) * 9 + (rr >> 1));      // deinterleave
        xlds[s] = ci * (XR * ROWP) + rp * ROWP + c;
    }
    const int wc0  = tid >> 5;          // 0..7
    const int wrem = tid & 31;
    const int woff0 = ((co0 + wc0) * CTOT + cib) * 16 + wrem;
    const int wlds0 = wc0 * (16 * WROWP) + wrem;

    // ---- prime prefetch for cc = 0 ----
    float pxv[NXS], pwv[NWS];
    #pragma unroll
    for (int s = 0; s < NXS; ++s) pxv[s] = xok[s] ? x[xoff[s]] : 0.0f;
    #pragma unroll
    for (int s = 0; s < NWS; ++s) pwv[s] = w[woff0 + s * (8 * CTOT * 16)];

    int xadd = 0, wadd = 0;
    const int xstride = KC * Hin * Win;

    for (int cc = 0; cc < NCC; ++cc) {
        #pragma unroll
        for (int s = 0; s < NXS; ++s) {
            if (tid + s * THREADS < XTOT) {
                xs_fl[xlds[s]] = pxv[s];
            }
        }
        #pragma unroll
        for (int s = 0; s < NWS; ++s)
            ws_f[wlds0 + s * WROWP] = pwv[s];
        __syncthreads();

        if (cc + 1 < NCC) {
            xadd += xstride;
            wadd += KC * 16;
            #pragma unroll
            for (int s = 0; s < NXS; ++s)
                pxv[s] = xok[s] ? x[xoff[s] + xadd] : 0.0f;
            #pragma unroll
            for (int s = 0; s < NWS; ++s)
                pwv[s] = w[woff0 + wadd + s * (8 * CTOT * 16)];
        }

        __builtin_amdgcn_s_setprio(1);
        #pragma unroll 1
        for (int ci = 0; ci < KC; ++ci) {
            #pragma unroll
            for (int kh = 0; kh < 4; ++kh) {
                // deinterleaved: rows kh+2*lho live at (kh&1)*9+(kh>>1)+lho
                const float* __restrict__ xr =
                    &xs[ci][(kh & 1) * 9 + (kh >> 1) + lho][2 * lwo];
                const float4 a0 = *(const float4*)(xr + 0);
                const float4 a1 = *(const float4*)(xr + 4);
                const float4 a2 = *(const float4*)(xr + 8);
                const float4 a3 = *(const float4*)(xr + 12);
                const float4 a4 = *(const float4*)(xr + 16);
                const float xf[20] = {a0.x, a0.y, a0.z, a0.w,
                                      a1.x, a1.y, a1.z, a1.w,
                                      a2.x, a2.y, a2.z, a2.w,
                                      a3.x, a3.y, a3.z, a3.w,
                                      a4.x, a4.y, a4.z, a4.w};
                const float* __restrict__ wbase =
                    &ws_f[cog * WROWP + ci * 16 + kh * 4];
                #pragma unroll
                for (int cl = 0; cl < 8; ++cl) {
                    const float4 wv = *(const float4*)(wbase + cl * 16 * WROWP);
                    #pragma unroll
                    for (int j = 0; j < 8; ++j) {
                        acc[cl][j] = fmaf(xf[2 * j + 0], wv.x, acc[cl][j]);
                        acc[cl][j] = fmaf(xf[2 * j + 1], wv.y, acc[cl][j]);
                        acc[cl][j] = fmaf(xf[2 * j + 2], wv.z, acc[cl][j]);
                        acc[cl][j] = fmaf(xf[2 * j + 3], wv.w, acc[cl][j]);
                    }
                }
            }
        }
        __builtin_amdgcn_s_setprio(0);
        __syncthreads();
    }

    // ---- epilogue ----
    float* __restrict__ yb = y;
    if (PARTIAL) yb += (size_t)blockIdx.y * (size_t)(B * Cout * Ho * Wo);
    #pragma unroll
    for (int cl = 0; cl < 8; ++cl) {
        float* __restrict__ yp =
            &yb[((b * Cout + co0 + cog * 8 + cl) * Ho + oh0 + lho) * Wo + ow0 + lwo];
        float4 r0, r1;
        if (PARTIAL) {
            r0 = make_float4(acc[cl][0], acc[cl][1], acc[cl][2], acc[cl][3]);
            r1 = make_float4(acc[cl][4], acc[cl][5], acc[cl][6], acc[cl][7]);
        } else {
            r0 = make_float4(fmaxf(acc[cl][0], 0.0f), fmaxf(acc[cl][1], 0.0f),
                             fmaxf(acc[cl][2], 0.0f), fmaxf(acc[cl][3], 0.0f));
            r1 = make_float4(fmaxf(acc[cl][4], 0.0f), fmaxf(acc[cl][5], 0.0f),
                             fmaxf(acc[cl][6], 0.0f), fmaxf(acc[cl][7], 0.0f));
        }
        *(float4*)yp       = r0;
        *(float4*)(yp + 4) = r1;
    }
}

// split-K reduce: y = relu(sum_s zp[i + s*plane] + bias[(i>>CSHIFT)&255])
template<int NS, int CSHIFT>
__global__ __launch_bounds__(THREADS)
void reduce_relu_kernel(const float* __restrict__ zp, const float* __restrict__ bias,
                        float* __restrict__ y, int plane) {
    int i = blockIdx.x * THREADS + threadIdx.x;
    float s = zp[i];
    #pragma unroll
    for (int k = 1; k < NS; ++k) s += zp[i + k * plane];
    s += bias[(i >> CSHIFT) & 255];
    y[i] = fmaxf(s, 0.0f);
}

// codebook row squared norms + init of packed argmin cells (fused)
__global__ __launch_bounds__(THREADS)
void cnorm_kernel(const float* __restrict__ cb, float* __restrict__ cn,
                  unsigned long long* __restrict__ packed) {
    int c = blockIdx.x * THREADS + threadIdx.x;   // 8192 rows
    const float* __restrict__ row = cb + c * 256;
    float s = 0.0f;
    for (int k = 0; k < 256; k += 4) {
        float4 v = *(const float4*)(row + k);
        s = fmaf(v.x, v.x, s);
        s = fmaf(v.y, v.y, s);
        s = fmaf(v.z, v.z, s);
        s = fmaf(v.w, v.w, s);
    }
    cn[c] = s;
    packed[c] = 0xFFFFFFFFFFFFFFFFULL;
}

// One-time codebook transpose: cbT[k][c] = cb[c][k]. 64x64 LDS tiles.
__global__ __launch_bounds__(THREADS)
void cbt_kernel(const float* __restrict__ cb, float* __restrict__ cbT) {
    __shared__ float tile[64][65];
    const int t  = threadIdx.x;
    const int c0 = blockIdx.x * 64;     // code base
    const int k0 = blockIdx.y * 64;     // k base
    const int r  = t >> 4;              // 0..15
    const int c  = (t & 15) * 4;        // 0..60
    #pragma unroll
    for (int i = 0; i < 4; ++i) {
        const int rr = r + i * 16;      // code within tile
        const float4 v = *(const float4*)(cb + (size_t)(c0 + rr) * 256 + k0 + c);
        tile[c + 0][rr] = v.x;
        tile[c + 1][rr] = v.y;
        tile[c + 2][rr] = v.z;
        tile[c + 3][rr] = v.w;
    }
    __syncthreads();
    #pragma unroll
    for (int i = 0; i < 4; ++i) {
        const int rr = r + i * 16;      // k within tile
        float4 v;
        v.x = tile[rr][c + 0];
        v.y = tile[rr][c + 1];
        v.z = tile[rr][c + 2];
        v.w = tile[rr][c + 3];
        *(float4*)(cbT + (size_t)(k0 + rr) * 8192 + c0 + c) = v;
    }
}

// ---------------------------------------------------------------------------
// VQ argmin, barrier-free streaming: zt[256][32] in LDS (broadcast reads);
// codebook read DIRECTLY from cbT per kk (8 unique 16B addrs/wave, L1/L2
// resident). No cl tile, no main-loop barriers -> waves free-run and loads
// schedule ahead. k-ascending fma chain on bit-identical values -> same
// distances -> same argmin. Grid 1024 = 4 blocks/CU exact (LDS 32KB).
// ---------------------------------------------------------------------------
#define VQ_CTILE 256
__global__ __launch_bounds__(THREADS, 4)
void vq_argmin_kernel(const float* __restrict__ z, const float* __restrict__ cbT,
                      const float* __restrict__ cnorm,
                      unsigned long long* __restrict__ packed) {
    __shared__ float zt[256][32];               // 32 KB, [k][q]

    const int t    = threadIdx.x;
    const int lane = t & 63;
    const int wv   = t >> 6;
    const int qg   = t & 7;             // 8 groups x 4 q
    const int cg   = t >> 3;            // 32 groups x 8 c
    const int qblk   = blockIdx.x >> 2;
    const int csplit = blockIdx.x & 3;
    const int q0  = qblk * 32;
    const int b   = q0 >> 8;
    const int hw0 = q0 & 255;

    {
        const float* __restrict__ zb = z + (b * 256) * 256 + hw0;
        #pragma unroll
        for (int i = 0; i < 8; ++i) {
            const int u = t + i * 256;
            const int k = u >> 3;
            const int m = u & 7;
            *(float4*)&zt[k][m * 4] = *(const float4*)(zb + k * 256 + m * 4);
        }
    }
    __syncthreads();                    // zt ready; no more barriers in loop

    float bd[4];
    int   bi[4];
    #pragma unroll
    for (int iq = 0; iq < 4; ++iq) { bd[iq] = 3.4e38f; bi[iq] = 0; }

    const int cbase = csplit * 2048;

    #pragma unroll 1
    for (int ct = 0; ct < 2048 / VQ_CTILE; ++ct) {      // 8 x 256-code tiles
        const int cb0 = cbase + ct * VQ_CTILE;
        const float* __restrict__ cp = cbT + cb0 + cg * 8;   // row k=0 slice

        float acc[4][8];
        #pragma unroll
        for (int iq = 0; iq < 4; ++iq)
            #pragma unroll
            for (int j = 0; j < 8; ++j) acc[iq][j] = 0.0f;

        #pragma unroll 1
        for (int k4 = 0; k4 < 64; ++k4) {       // 64 groups of 4 k
            #pragma unroll
            for (int u = 0; u < 4; ++u) {
                const int kk = k4 * 4 + u;
                const float4 zv = *(const float4*)&zt[kk][qg * 4];
                const float* __restrict__ s = cp + (size_t)kk * 8192;
                const float4 c0 = *(const float4*)(s);
                const float4 c1 = *(const float4*)(s + 4);
                acc[0][0] = fmaf(zv.x, c0.x, acc[0][0]);
                acc[1][0] = fmaf(zv.y, c0.x, acc[1][0]);
                acc[2][0] = fmaf(zv.z, c0.x, acc[2][0]);
                acc[3][0] = fmaf(zv.w, c0.x, acc[3][0]);
                acc[0][1] = fmaf(zv.x, c0.y, acc[0][1]);
                acc[1][1] = fmaf(zv.y, c0.y, acc[1][1]);
                acc[2][1] = fmaf(zv.z, c0.y, acc[2][1]);
                acc[3][1] = fmaf(zv.w, c0.y, acc[3][1]);
                acc[0][2] = fmaf(zv.x, c0.z, acc[0][2]);
                acc[1][2] = fmaf(zv.y, c0.z, acc[1][2]);
                acc[2][2] = fmaf(zv.z, c0.z, acc[2][2]);
                acc[3][2] = fmaf(zv.w, c0.z, acc[3][2]);
                acc[0][3] = fmaf(zv.x, c0.w, acc[0][3]);
                acc[1][3] = fmaf(zv.y, c0.w, acc[1][3]);
                acc[2][3] = fmaf(zv.z, c0.w, acc[2][3]);
                acc[3][3] = fmaf(zv.w, c0.w, acc[3][3]);
                acc[0][4] = fmaf(zv.x, c1.x, acc[0][4]);
                acc[1][4] = fmaf(zv.y, c1.x, acc[1][4]);
                acc[2][4] = fmaf(zv.z, c1.x, acc[2][4]);
                acc[3][4] = fmaf(zv.w, c1.x, acc[3][4]);
                acc[0][5] = fmaf(zv.x, c1.y, acc[0][5]);
                acc[1][5] = fmaf(zv.y, c1.y, acc[1][5]);
                acc[2][5] = fmaf(zv.z, c1.y, acc[2][5]);
                acc[3][5] = fmaf(zv.w, c1.y, acc[3][5]);
                acc[0][6] = fmaf(zv.x, c1.z, acc[0][6]);
                acc[1][6] = fmaf(zv.y, c1.z, acc[1][6]);
                acc[2][6] = fmaf(zv.z, c1.z, acc[2][6]);
                acc[3][6] = fmaf(zv.w, c1.z, acc[3][6]);
                acc[0][7] = fmaf(zv.x, c1.w, acc[0][7]);
                acc[1][7] = fmaf(zv.y, c1.w, acc[1][7]);
                acc[2][7] = fmaf(zv.z, c1.w, acc[2][7]);
                acc[3][7] = fmaf(zv.w, c1.w, acc[3][7]);
            }
        }

        // ---- d = ||c||^2 - 2 z.c ; running lexicographic min ----
        #pragma unroll
        for (int j = 0; j < 8; ++j) {
            const int c = cb0 + cg * 8 + j;
            const float cn = cnorm[c];
            #pragma unroll
            for (int iq = 0; iq < 4; ++iq) {
                const float d = fmaf(-2.0f, acc[iq][j], cn);
                if (d < bd[iq]) { bd[iq] = d; bi[iq] = c; }
            }
        }
    }

    // ---- intra-wave lex reduce over cg bits (lane bits 3..5) ----
    #pragma unroll
    for (int off = 8; off <= 32; off <<= 1) {
        #pragma unroll
        for (int iq = 0; iq < 4; ++iq) {
            const float od = __shfl_xor(bd[iq], off);
            const int   oi = __shfl_xor(bi[iq], off);
            if (od < bd[iq] || (od == bd[iq] && oi < bi[iq])) {
                bd[iq] = od; bi[iq] = oi;
            }
        }
    }

    // ---- cross-wave reduce via scratch aliased into dead zt ----
    __syncthreads();                    // all compute reads of zt done
    float* __restrict__ pd = &zt[0][0];
    int*   __restrict__ pi = (int*)(&zt[0][0] + 128);
    if (lane < 8) {
        #pragma unroll
        for (int iq = 0; iq < 4; ++iq) {
            pd[(wv * 8 + qg) * 4 + iq] = bd[iq];
            pi[(wv * 8 + qg) * 4 + iq] = bi[iq];
        }
    }
    __syncthreads();
    if (t < 32) {
        const int qq = t >> 2;
        const int iq = t & 3;
        float best = pd[(0 * 8 + qq) * 4 + iq];
        int   besti = pi[(0 * 8 + qq) * 4 + iq];
        #pragma unroll
        for (int w2 = 1; w2 < 4; ++w2) {
            const float d = pd[(w2 * 8 + qq) * 4 + iq];
            const int  i2 = pi[(w2 * 8 + qq) * 4 + iq];
            if (d < best || (d == best && i2 < besti)) { best = d; besti = i2; }
        }
        unsigned int k = __float_as_uint(best);
        k = (k & 0x80000000u) ? ~k : (k | 0x80000000u);
        const unsigned long long pkv =
            ((unsigned long long)k << 32) | (unsigned int)besti;
        atomicMin(&packed[q0 + qq * 4 + iq], pkv);
    }
}

// Epilogue: out[0:2097152] = codebook[idx] in NCHW; out[2097152:] = (float)idx.
__global__ __launch_bounds__(THREADS)
void gather_kernel(const float* __restrict__ cb,
                   const unsigned long long* __restrict__ packed,
                   float* __restrict__ out) {
    int i = blockIdx.x * THREADS + threadIdx.x;
    if (i < 32 * 256 * 16 * 16) {
        int w = i & 15;
        int h = (i >> 4) & 15;
        int c = (i >> 8) & 255;
        int b = i >> 16;
        int n = (b << 8) | (h << 4) | w;
        int idx = (int)(packed[n] & 0xFFFFFFFFULL);
        out[i] = cb[idx * 256 + c];
    }
    if (i < 8192) {
        int idx = (int)(packed[i] & 0xFFFFFFFFULL);
        out[32 * 256 * 16 * 16 + i] = (float)idx;
    }
}

extern "C" void kernel_launch(void* const* d_in, const int* in_sizes, int n_in,
                              void* d_out, int out_size, void* d_ws, size_t ws_size,
                              hipStream_t stream) {
    const float* x  = (const float*)d_in[0];
    const float* w1 = (const float*)d_in[1];
    const float* b1 = (const float*)d_in[2];
    const float* w2 = (const float*)d_in[3];
    const float* b2 = (const float*)d_in[4];
    const float* w3 = (const float*)d_in[5];
    const float* b3 = (const float*)d_in[6];
    const float* w4 = (const float*)d_in[7];
    const float* b4 = (const float*)d_in[8];
    const float* cb = (const float*)d_in[9];
    float* out = (float*)d_out;

    char* ws = (char*)d_ws;
    // z1 : 128MB @ 0            (conv1 out; dead after conv2)
    // z2 :  64MB @ 134217728   (conv2 out; dead after conv3p)
    // zp3:  64MB @ 0            (2 x 32MB partials; inside dead z1)
    // z3 :  32MB @ 67108864    (reduce3 out; dead after conv4p)
    // zp4:  64MB @ 0            (8 x 8MB partials; zp3 dead)
    // cbT:   8MB @ 67108864    (transpose, written after conv4p; z3 dead)
    // z4 :   8MB @ 134217728   (reduce4 out; z2 dead)
    // cn : 32KB @ 142606336 ; packed: 64KB @ 0 (zp4 dead once cnorm runs)
    float* z1  = (float*)(ws);
    float* z2  = (float*)(ws + 134217728);
    float* zp3 = (float*)(ws);
    float* z3  = (float*)(ws + 67108864);
    float* zp4 = (float*)(ws);
    float* cbt = (float*)(ws + 67108864);
    float* z4  = (float*)(ws + 134217728);
    float* cn  = (float*)(ws + 142606336);
    unsigned long long* pk = (unsigned long long*)(ws);

    // conv1: (32,3,256,256) -> (32,64,128,128)  old template, grid 4096
    conv_tiled_kernel<3, 3, 3, false, 48><<<32 * 1 * 16 * 8, THREADS, 0, stream>>>(
        x, w1, b1, z1, 32, 64, 256, 256, 1, 16, 8);
    // conv2: -> (32,128,64,64)  pipelined 128-co tile, grid 1024 = 4/CU exact
    conv_tiled8_kernel<64, 2, 64, false><<<32 * 1 * 8 * 4, THREADS, 0, stream>>>(
        z1, w2, b2, z2, 32, 128, 128, 128, 1, 8, 4);
    // conv3: -> partials (2 x 64ci), grid (512,2) = 1024
    conv_tiled8_kernel<64, 2, 128, true><<<dim3(32 * 2 * 4 * 2, 2), THREADS, 0, stream>>>(
        z2, w3, b3, zp3, 32, 256, 64, 64, 2, 4, 2);
    reduce_relu_kernel<2, 10><<<(32 * 256 * 32 * 32) / THREADS, THREADS, 0, stream>>>(
        zp3, b3, z3, 32 * 256 * 32 * 32);
    // conv4: -> partials (8 x 32ci), grid (128,8) = 1024
    conv_tiled8_kernel<32, 2, 256, true><<<dim3(32 * 2 * 2 * 1, 8), THREADS, 0, stream>>>(
        z3, w4, b4, zp4, 32, 256, 32, 32, 2, 2, 1);
    // z3 dead now -> transpose codebook into its region
    cbt_kernel<<<dim3(128, 4), THREADS, 0, stream>>>(cb, cbt);
    reduce_relu_kernel<8, 8><<<(32 * 256 * 16 * 16) / THREADS, THREADS, 0, stream>>>(
        zp4, b4, z4, 32 * 256 * 16 * 16);

    // VQ (cnorm fuses the packed-cell init)
    cnorm_kernel<<<8192 / THREADS, THREADS, 0, stream>>>(cb, cn, pk);
    vq_argmin_kernel<<<256 * 4, THREADS, 0, stream>>>(z4, cbt, cn, pk);

    // epilogue
    gather_kernel<<<(32 * 256 * 16 * 16) / THREADS, THREADS, 0, stream>>>(cb, pk, out);
}

// Round 19
// 1524.512 us; speedup vs baseline: 1.0430x; 1.0430x over previous
//
#include <hip/hip_runtime.h>

// ---------------------------------------------------------------------------
// VQ-VAE encoder: 4x [conv k=4 s=2 p=1 + ReLU] then nearest-codebook lookup.
// Round 19 (FINAL): restore the round-15/17 measured-best configuration
// (1525-1526us, reproduced twice; session 24177 -> 1525, 15.9x).
// r18's barrier-free streaming VQ regressed (+125us): removing the cl LDS
// tile multiplied VMEM instructions 8x (512 vs 64 global loads per 256-k
// sweep) -- the LDS staging amortizes vector-memory issue, not just cache
// traffic. VQ structural ledger 0-for-6; this structure is the local optimum.
// Per-kernel state:
//  conv1: 4co x 8wo LDS tile (CIN=3).
//  conv2/3/4: 8co x 8wo 128-co tile, permuted-row ws LDS (conflict-free),
//    parity-deinterleaved xs rows, T14 register prefetch with cc-invariant
//    addressing, split-K conv3(x2)/conv4(x8), setprio around fma cluster.
//  vq: 4q x 8c tile, zt[256][32] LDS + 8k x 256c cl chunk staged from the
//    one-time cbT transpose (coalesced), exact 4-block/CU residency,
//    lex-(d,idx) shfl reduce + packed u64 atomicMin.
// Distances bitwise stable all session (absmax 0.0 every round).
// ---------------------------------------------------------------------------

#define THREADS 256

// ---- old 4co x 8wo template (used only for conv1, CIN=3) ----
template<int CINR, int KC, int CTOT, bool PARTIAL, int WROWP>
__global__ __launch_bounds__(THREADS)
void conv_tiled_kernel(const float* __restrict__ x, const float* __restrict__ w,
                       const float* __restrict__ bias, float* __restrict__ y,
                       int B, int Cout, int Hin, int Win,
                       int nCt, int nHt, int nWt) {
    constexpr int TH = 8, TW = 16, TC = 64;
    constexpr int XR = 2 * TH + 2;
    constexpr int XC = 2 * TW + 2;
    constexpr int ROWP = 36;
    constexpr int XTOT = KC * XR * ROWP;
    constexpr int WROW16 = KC * 16;
    constexpr int WTOT = TC * WROW16;

    __shared__ float xs[KC][XR][ROWP];
    __shared__ float ws_f[TC * WROWP];

    const int Ho = Hin >> 1, Wo = Win >> 1;

    int id = blockIdx.x;
    const int wt = id % nWt; id /= nWt;
    const int ht = id % nHt; id /= nHt;
    const int ct = id % nCt; const int b = id / nCt;
    const int cib = blockIdx.y * CINR;

    const int oh0 = ht * TH, ow0 = wt * TW, co0 = ct * TC;
    const int h0 = 2 * oh0 - 1;
    const int w0 = 2 * ow0 - 1;

    const int tid  = threadIdx.x;
    const int co_l = (tid >> 4) * 4;
    const int sp   = tid & 15;
    const int lho  = sp >> 1;
    const int lwo  = (sp & 1) * 8;

    float acc[4][8];
    #pragma unroll
    for (int co = 0; co < 4; ++co) {
        const float bv = PARTIAL ? 0.0f : bias[co0 + co_l + co];
        #pragma unroll
        for (int j = 0; j < 8; ++j) acc[co][j] = bv;
    }

    float* __restrict__ xs_fl = &xs[0][0][0];

    for (int cc = 0; cc < CINR / KC; ++cc) {
        const int ci0 = cc * KC;

        for (int j = tid; j < XTOT; j += THREADS) {
            const int ci = j / (XR * ROWP);
            const int rr = (j - ci * (XR * ROWP)) / ROWP;
            const int c  = j % ROWP;
            const int hi = h0 + rr;
            const int wi = w0 + c;
            float v = 0.0f;
            if (c < XC && (unsigned)hi < (unsigned)Hin && (unsigned)wi < (unsigned)Win)
                v = x[((b * CTOT + cib + ci0 + ci) * Hin + hi) * Win + wi];
            xs_fl[j] = v;
        }
        for (int j = tid; j < WTOT; j += THREADS) {
            const int co  = j / WROW16;
            const int rem = j - co * WROW16;
            ws_f[co * WROWP + rem] = w[((co0 + co) * CTOT + cib + ci0) * 16 + rem];
        }
        __syncthreads();

        #pragma unroll 1
        for (int ci = 0; ci < KC; ++ci) {
            #pragma unroll
            for (int kh = 0; kh < 4; ++kh) {
                const float* __restrict__ xr = &xs[ci][2 * lho + kh][2 * lwo];
                const float4 a0 = *(const float4*)(xr + 0);
                const float4 a1 = *(const float4*)(xr + 4);
                const float4 a2 = *(const float4*)(xr + 8);
                const float4 a3 = *(const float4*)(xr + 12);
                const float4 a4 = *(const float4*)(xr + 16);
                const float xf[20] = {a0.x, a0.y, a0.z, a0.w,
                                      a1.x, a1.y, a1.z, a1.w,
                                      a2.x, a2.y, a2.z, a2.w,
                                      a3.x, a3.y, a3.z, a3.w,
                                      a4.x, a4.y, a4.z, a4.w};
                #pragma unroll
                for (int co = 0; co < 4; ++co) {
                    const float4 wv =
                        *(const float4*)&ws_f[(co_l + co) * WROWP + ci * 16 + kh * 4];
                    #pragma unroll
                    for (int j = 0; j < 8; ++j) {
                        acc[co][j] = fmaf(xf[2 * j + 0], wv.x, acc[co][j]);
                        acc[co][j] = fmaf(xf[2 * j + 1], wv.y, acc[co][j]);
                        acc[co][j] = fmaf(xf[2 * j + 2], wv.z, acc[co][j]);
                        acc[co][j] = fmaf(xf[2 * j + 3], wv.w, acc[co][j]);
                    }
                }
            }
        }
        __syncthreads();
    }

    float* __restrict__ yb = y;
    if (PARTIAL) yb += (size_t)blockIdx.y * (size_t)(B * Cout * Ho * Wo);
    #pragma unroll
    for (int co = 0; co < 4; ++co) {
        float* __restrict__ yp =
            &yb[((b * Cout + co0 + co_l + co) * Ho + oh0 + lho) * Wo + ow0 + lwo];
        float4 r0, r1;
        if (PARTIAL) {
            r0 = make_float4(acc[co][0], acc[co][1], acc[co][2], acc[co][3]);
            r1 = make_float4(acc[co][4], acc[co][5], acc[co][6], acc[co][7]);
        } else {
            r0 = make_float4(fmaxf(acc[co][0], 0.0f), fmaxf(acc[co][1], 0.0f),
                             fmaxf(acc[co][2], 0.0f), fmaxf(acc[co][3], 0.0f));
            r1 = make_float4(fmaxf(acc[co][4], 0.0f), fmaxf(acc[co][5], 0.0f),
                             fmaxf(acc[co][6], 0.0f), fmaxf(acc[co][7], 0.0f));
        }
        *(float4*)yp       = r0;
        *(float4*)(yp + 4) = r1;
    }
}

// ---- 8co x 8wo template, 128-co block tile, T14 pipeline, deint-xs ----
template<int CINR, int KC, int CTOT, bool PARTIAL>
__global__ __launch_bounds__(THREADS)
void conv_tiled8_kernel(const float* __restrict__ x, const float* __restrict__ w,
                        const float* __restrict__ bias, float* __restrict__ y,
                        int B, int Cout, int Hin, int Win,
                        int nCt, int nHt, int nWt) {
    constexpr int TH = 8, TW = 16, TC = 128;
    constexpr int XR = 2 * TH + 2;      // 18
    constexpr int XC = 2 * TW + 2;      // 34
    constexpr int ROWP = 36;
    constexpr int XTOT = KC * XR * ROWP;            // 1296 @ KC=2
    constexpr int NXS  = (XTOT + THREADS - 1) / THREADS;  // 6
    constexpr int WROW16 = KC * 16;     // 32
    constexpr int WROWP  = KC * 16 + 4; // 36
    constexpr int NWS  = TC * WROW16 / THREADS;     // 16
    constexpr int NCC  = CINR / KC;

    __shared__ float xs[KC][XR][ROWP];  // 5.1 KB @ KC=2 (rows deinterleaved)
    __shared__ float ws_f[TC * WROWP];  // 18.4 KB @ KC=2

    const int Ho = Hin >> 1, Wo = Win >> 1;

    int id = blockIdx.x;
    const int wt = id % nWt; id /= nWt;
    const int ht = id % nHt; id /= nHt;
    const int ct = id % nCt; const int b = id / nCt;
    const int cib = blockIdx.y * CINR;

    const int oh0 = ht * TH, ow0 = wt * TW, co0 = ct * TC;
    const int h0 = 2 * oh0 - 1;
    const int w0 = 2 * ow0 - 1;

    const int tid = threadIdx.x;
    const int cog = tid >> 4;           // 16 groups x 8 co
    const int sp  = tid & 15;
    const int lho = sp >> 1;            // 0..7
    const int lwo = (sp & 1) * 8;       // 0 or 8

    float acc[8][8];
    #pragma unroll
    for (int cl = 0; cl < 8; ++cl) {
        const float bv = PARTIAL ? 0.0f : bias[co0 + cog * 8 + cl];
        #pragma unroll
        for (int j = 0; j < 8; ++j) acc[cl][j] = bv;
    }

    float* __restrict__ xs_fl = &xs[0][0][0];

    // ---- cc-invariant staging descriptors (incl. deinterleaved LDS idx) ----
    int  xoff[NXS];
    int  xlds[NXS];
    bool xok[NXS];
    #pragma unroll
    for (int s = 0; s < NXS; ++s) {
        const int j  = tid + s * THREADS;
        const int ci = j / (XR * ROWP);
        const int rr = (j - ci * (XR * ROWP)) / ROWP;
        const int c  = j % ROWP;
        const int hi = h0 + rr;
        const int wi = w0 + c;
        const bool ok = (j < XTOT) && (c < XC) &&
                        ((unsigned)hi < (unsigned)Hin) &&
                        ((unsigned)wi < (unsigned)Win);
        xok[s]  = ok;
        xoff[s] = ok ? (((b * CTOT + cib + ci) * Hin + hi) * Win + wi) : 0;
        const int rp = ((rr & 1) * 9 + (rr >> 1));      // deinterleave
        xlds[s] = ci * (XR * ROWP) + rp * ROWP + c;
    }
    const int wc0  = tid >> 5;          // 0..7
    const int wrem = tid & 31;
    const int woff0 = ((co0 + wc0) * CTOT + cib) * 16 + wrem;
    const int wlds0 = wc0 * (16 * WROWP) + wrem;

    // ---- prime prefetch for cc = 0 ----
    float pxv[NXS], pwv[NWS];
    #pragma unroll
    for (int s = 0; s < NXS; ++s) pxv[s] = xok[s] ? x[xoff[s]] : 0.0f;
    #pragma unroll
    for (int s = 0; s < NWS; ++s) pwv[s] = w[woff0 + s * (8 * CTOT * 16)];

    int xadd = 0, wadd = 0;
    const int xstride = KC * Hin * Win;

    for (int cc = 0; cc < NCC; ++cc) {
        #pragma unroll
        for (int s = 0; s < NXS; ++s) {
            if (tid + s * THREADS < XTOT) {
                xs_fl[xlds[s]] = pxv[s];
            }
        }
        #pragma unroll
        for (int s = 0; s < NWS; ++s)
            ws_f[wlds0 + s * WROWP] = pwv[s];
        __syncthreads();

        if (cc + 1 < NCC) {
            xadd += xstride;
            wadd += KC * 16;
            #pragma unroll
            for (int s = 0; s < NXS; ++s)
                pxv[s] = xok[s] ? x[xoff[s] + xadd] : 0.0f;
            #pragma unroll
            for (int s = 0; s < NWS; ++s)
                pwv[s] = w[woff0 + wadd + s * (8 * CTOT * 16)];
        }

        __builtin_amdgcn_s_setprio(1);
        #pragma unroll 1
        for (int ci = 0; ci < KC; ++ci) {
            #pragma unroll
            for (int kh = 0; kh < 4; ++kh) {
                // deinterleaved: rows kh+2*lho live at (kh&1)*9+(kh>>1)+lho
                const float* __restrict__ xr =
                    &xs[ci][(kh & 1) * 9 + (kh >> 1) + lho][2 * lwo];
                const float4 a0 = *(const float4*)(xr + 0);
                const float4 a1 = *(const float4*)(xr + 4);
                const float4 a2 = *(const float4*)(xr + 8);
                const float4 a3 = *(const float4*)(xr + 12);
                const float4 a4 = *(const float4*)(xr + 16);
                const float xf[20] = {a0.x, a0.y, a0.z, a0.w,
                                      a1.x, a1.y, a1.z, a1.w,
                                      a2.x, a2.y, a2.z, a2.w,
                                      a3.x, a3.y, a3.z, a3.w,
                                      a4.x, a4.y, a4.z, a4.w};
                const float* __restrict__ wbase =
                    &ws_f[cog * WROWP + ci * 16 + kh * 4];
                #pragma unroll
                for (int cl = 0; cl < 8; ++cl) {
                    const float4 wv = *(const float4*)(wbase + cl * 16 * WROWP);
                    #pragma unroll
                    for (int j = 0; j < 8; ++j) {
                        acc[cl][j] = fmaf(xf[2 * j + 0], wv.x, acc[cl][j]);
                        acc[cl][j] = fmaf(xf[2 * j + 1], wv.y, acc[cl][j]);
                        acc[cl][j] = fmaf(xf[2 * j + 2], wv.z, acc[cl][j]);
                        acc[cl][j] = fmaf(xf[2 * j + 3], wv.w, acc[cl][j]);
                    }
                }
            }
        }
        __builtin_amdgcn_s_setprio(0);
        __syncthreads();
    }

    // ---- epilogue ----
    float* __restrict__ yb = y;
    if (PARTIAL) yb += (size_t)blockIdx.y * (size_t)(B * Cout * Ho * Wo);
    #pragma unroll
    for (int cl = 0; cl < 8; ++cl) {
        float* __restrict__ yp =
            &yb[((b * Cout + co0 + cog * 8 + cl) * Ho + oh0 + lho) * Wo + ow0 + lwo];
        float4 r0, r1;
        if (PARTIAL) {
            r0 = make_float4(acc[cl][0], acc[cl][1], acc[cl][2], acc[cl][3]);
            r1 = make_float4(acc[cl][4], acc[cl][5], acc[cl][6], acc[cl][7]);
        } else {
            r0 = make_float4(fmaxf(acc[cl][0], 0.0f), fmaxf(acc[cl][1], 0.0f),
                             fmaxf(acc[cl][2], 0.0f), fmaxf(acc[cl][3], 0.0f));
            r1 = make_float4(fmaxf(acc[cl][4], 0.0f), fmaxf(acc[cl][5], 0.0f),
                             fmaxf(acc[cl][6], 0.0f), fmaxf(acc[cl][7], 0.0f));
        }
        *(float4*)yp       = r0;
        *(float4*)(yp + 4) = r1;
    }
}

// split-K reduce: y = relu(sum_s zp[i + s*plane] + bias[(i>>CSHIFT)&255])
template<int NS, int CSHIFT>
__global__ __launch_bounds__(THREADS)
void reduce_relu_kernel(const float* __restrict__ zp, const float* __restrict__ bias,
                        float* __restrict__ y, int plane) {
    int i = blockIdx.x * THREADS + threadIdx.x;
    float s = zp[i];
    #pragma unroll
    for (int k = 1; k < NS; ++k) s += zp[i + k * plane];
    s += bias[(i >> CSHIFT) & 255];
    y[i] = fmaxf(s, 0.0f);
}

// codebook row squared norms + init of packed argmin cells (fused)
__global__ __launch_bounds__(THREADS)
void cnorm_kernel(const float* __restrict__ cb, float* __restrict__ cn,
                  unsigned long long* __restrict__ packed) {
    int c = blockIdx.x * THREADS + threadIdx.x;   // 8192 rows
    const float* __restrict__ row = cb + c * 256;
    float s = 0.0f;
    for (int k = 0; k < 256; k += 4) {
        float4 v = *(const float4*)(row + k);
        s = fmaf(v.x, v.x, s);
        s = fmaf(v.y, v.y, s);
        s = fmaf(v.z, v.z, s);
        s = fmaf(v.w, v.w, s);
    }
    cn[c] = s;
    packed[c] = 0xFFFFFFFFFFFFFFFFULL;
}

// One-time codebook transpose: cbT[k][c] = cb[c][k]. 64x64 LDS tiles.
__global__ __launch_bounds__(THREADS)
void cbt_kernel(const float* __restrict__ cb, float* __restrict__ cbT) {
    __shared__ float tile[64][65];
    const int t  = threadIdx.x;
    const int c0 = blockIdx.x * 64;     // code base
    const int k0 = blockIdx.y * 64;     // k base
    const int r  = t >> 4;              // 0..15
    const int c  = (t & 15) * 4;        // 0..60
    #pragma unroll
    for (int i = 0; i < 4; ++i) {
        const int rr = r + i * 16;      // code within tile
        const float4 v = *(const float4*)(cb + (size_t)(c0 + rr) * 256 + k0 + c);
        tile[c + 0][rr] = v.x;
        tile[c + 1][rr] = v.y;
        tile[c + 2][rr] = v.z;
        tile[c + 3][rr] = v.w;
    }
    __syncthreads();
    #pragma unroll
    for (int i = 0; i < 4; ++i) {
        const int rr = r + i * 16;      // k within tile
        float4 v;
        v.x = tile[rr][c + 0];
        v.y = tile[rr][c + 1];
        v.z = tile[rr][c + 2];
        v.w = tile[rr][c + 3];
        *(float4*)(cbT + (size_t)(k0 + rr) * 8192 + c0 + c) = v;
    }
}

// ---------------------------------------------------------------------------
// VQ argmin (round-15/17 version: cbT coalesced staging; measured best).
// ---------------------------------------------------------------------------
#define VQ_KCH 8
#define VQ_CTILE 256
__global__ __launch_bounds__(THREADS, 4)
void vq_argmin_kernel(const float* __restrict__ z, const float* __restrict__ cbT,
                      const float* __restrict__ cnorm,
                      unsigned long long* __restrict__ packed) {
    __shared__ float zt[256][32];               // 32 KB, [k][q]
    __shared__ float cl[VQ_KCH][VQ_CTILE];      //  8 KB, [k][c] (transposed)

    const int t    = threadIdx.x;
    const int lane = t & 63;
    const int wv   = t >> 6;
    const int qg   = t & 7;
    const int cg   = t >> 3;
    const int qblk   = blockIdx.x >> 2;
    const int csplit = blockIdx.x & 3;
    const int q0  = qblk * 32;
    const int b   = q0 >> 8;
    const int hw0 = q0 & 255;

    {
        const float* __restrict__ zb = z + (b * 256) * 256 + hw0;
        #pragma unroll
        for (int i = 0; i < 8; ++i) {
            const int u = t + i * 256;
            const int k = u >> 3;
            const int m = u & 7;
            *(float4*)&zt[k][m * 4] = *(const float4*)(zb + k * 256 + m * 4);
        }
    }

    float bd[4];
    int   bi[4];
    #pragma unroll
    for (int iq = 0; iq < 4; ++iq) { bd[iq] = 3.4e38f; bi[iq] = 0; }

    const int cbase = csplit * 2048;
    const int srow  = t >> 5;           // 0..7 (k within chunk)
    const int scol  = (t & 31) * 8;     // 0..248 (8 codes per thread)

    #pragma unroll 1
    for (int ct = 0; ct < 2048 / VQ_CTILE; ++ct) {
        const int cb0 = cbase + ct * VQ_CTILE;

        float acc[4][8];
        #pragma unroll
        for (int iq = 0; iq < 4; ++iq)
            #pragma unroll
            for (int j = 0; j < 8; ++j) acc[iq][j] = 0.0f;

        #pragma unroll 1
        for (int kc = 0; kc < 256 / VQ_KCH; ++kc) {
            __syncthreads();
            // ---- stage chunk from cbT: 8 coalesced 1KB rows ----
            {
                const float* __restrict__ s =
                    cbT + (size_t)(kc * VQ_KCH + srow) * 8192 + cb0 + scol;
                const float4 v0 = *(const float4*)(s);
                const float4 v1 = *(const float4*)(s + 4);
                *(float4*)&cl[srow][scol]     = v0;
                *(float4*)&cl[srow][scol + 4] = v1;
            }
            __syncthreads();

            __builtin_amdgcn_s_setprio(1);
            const int kb = kc * VQ_KCH;
            #pragma unroll
            for (int kk = 0; kk < VQ_KCH; ++kk) {
                const float4 zv = *(const float4*)&zt[kb + kk][qg * 4];
                const float4 c0 = *(const float4*)&cl[kk][cg * 8];
                const float4 c1 = *(const float4*)&cl[kk][cg * 8 + 4];
                acc[0][0] = fmaf(zv.x, c0.x, acc[0][0]);
                acc[1][0] = fmaf(zv.y, c0.x, acc[1][0]);
                acc[2][0] = fmaf(zv.z, c0.x, acc[2][0]);
                acc[3][0] = fmaf(zv.w, c0.x, acc[3][0]);
                acc[0][1] = fmaf(zv.x, c0.y, acc[0][1]);
                acc[1][1] = fmaf(zv.y, c0.y, acc[1][1]);
                acc[2][1] = fmaf(zv.z, c0.y, acc[2][1]);
                acc[3][1] = fmaf(zv.w, c0.y, acc[3][1]);
                acc[0][2] = fmaf(zv.x, c0.z, acc[0][2]);
                acc[1][2] = fmaf(zv.y, c0.z, acc[1][2]);
                acc[2][2] = fmaf(zv.z, c0.z, acc[2][2]);
                acc[3][2] = fmaf(zv.w, c0.z, acc[3][2]);
                acc[0][3] = fmaf(zv.x, c0.w, acc[0][3]);
                acc[1][3] = fmaf(zv.y, c0.w, acc[1][3]);
                acc[2][3] = fmaf(zv.z, c0.w, acc[2][3]);
                acc[3][3] = fmaf(zv.w, c0.w, acc[3][3]);
                acc[0][4] = fmaf(zv.x, c1.x, acc[0][4]);
                acc[1][4] = fmaf(zv.y, c1.x, acc[1][4]);
                acc[2][4] = fmaf(zv.z, c1.x, acc[2][4]);
                acc[3][4] = fmaf(zv.w, c1.x, acc[3][4]);
                acc[0][5] = fmaf(zv.x, c1.y, acc[0][5]);
                acc[1][5] = fmaf(zv.y, c1.y, acc[1][5]);
                acc[2][5] = fmaf(zv.z, c1.y, acc[2][5]);
                acc[3][5] = fmaf(zv.w, c1.y, acc[3][5]);
                acc[0][6] = fmaf(zv.x, c1.z, acc[0][6]);
                acc[1][6] = fmaf(zv.y, c1.z, acc[1][6]);
                acc[2][6] = fmaf(zv.z, c1.z, acc[2][6]);
                acc[3][6] = fmaf(zv.w, c1.z, acc[3][6]);
                acc[0][7] = fmaf(zv.x, c1.w, acc[0][7]);
                acc[1][7] = fmaf(zv.y, c1.w, acc[1][7]);
                acc[2][7] = fmaf(zv.z, c1.w, acc[2][7]);
                acc[3][7] = fmaf(zv.w, c1.w, acc[3][7]);
            }
            __builtin_amdgcn_s_setprio(0);
        }

        #pragma unroll
        for (int j = 0; j < 8; ++j) {
            const int c = cb0 + cg * 8 + j;
            const float cn = cnorm[c];
            #pragma unroll
            for (int iq = 0; iq < 4; ++iq) {
                const float d = fmaf(-2.0f, acc[iq][j], cn);
                if (d < bd[iq]) { bd[iq] = d; bi[iq] = c; }
            }
        }
    }

    #pragma unroll
    for (int off = 8; off <= 32; off <<= 1) {
        #pragma unroll
        for (int iq = 0; iq < 4; ++iq) {
            const float od = __shfl_xor(bd[iq], off);
            const int   oi = __shfl_xor(bi[iq], off);
            if (od < bd[iq] || (od == bd[iq] && oi < bi[iq])) {
                bd[iq] = od; bi[iq] = oi;
            }
        }
    }

    __syncthreads();
    float* __restrict__ pd = &zt[0][0];
    int*   __restrict__ pi = (int*)(&zt[0][0] + 128);
    if (lane < 8) {
        #pragma unroll
        for (int iq = 0; iq < 4; ++iq) {
            pd[(wv * 8 + qg) * 4 + iq] = bd[iq];
            pi[(wv * 8 + qg) * 4 + iq] = bi[iq];
        }
    }
    __syncthreads();
    if (t < 32) {
        const int qq = t >> 2;
        const int iq = t & 3;
        float best = pd[(0 * 8 + qq) * 4 + iq];
        int   besti = pi[(0 * 8 + qq) * 4 + iq];
        #pragma unroll
        for (int w2 = 1; w2 < 4; ++w2) {
            const float d = pd[(w2 * 8 + qq) * 4 + iq];
            const int  i2 = pi[(w2 * 8 + qq) * 4 + iq];
            if (d < best || (d == best && i2 < besti)) { best = d; besti = i2; }
        }
        unsigned int k = __float_as_uint(best);
        k = (k & 0x80000000u) ? ~k : (k | 0x80000000u);
        const unsigned long long pkv =
            ((unsigned long long)k << 32) | (unsigned int)besti;
        atomicMin(&packed[q0 + qq * 4 + iq], pkv);
    }
}

// Epilogue: out[0:2097152] = codebook[idx] in NCHW; out[2097152:] = (float)idx.
__global__ __launch_bounds__(THREADS)
void gather_kernel(const float* __restrict__ cb,
                   const unsigned long long* __restrict__ packed,
                   float* __restrict__ out) {
    int i = blockIdx.x * THREADS + threadIdx.x;
    if (i < 32 * 256 * 16 * 16) {
        int w = i & 15;
        int h = (i >> 4) & 15;
        int c = (i >> 8) & 255;
        int b = i >> 16;
        int n = (b << 8) | (h << 4) | w;
        int idx = (int)(packed[n] & 0xFFFFFFFFULL);
        out[i] = cb[idx * 256 + c];
    }
    if (i < 8192) {
        int idx = (int)(packed[i] & 0xFFFFFFFFULL);
        out[32 * 256 * 16 * 16 + i] = (float)idx;
    }
}

extern "C" void kernel_launch(void* const* d_in, const int* in_sizes, int n_in,
                              void* d_out, int out_size, void* d_ws, size_t ws_size,
                              hipStream_t stream) {
    const float* x  = (const float*)d_in[0];
    const float* w1 = (const float*)d_in[1];
    const float* b1 = (const float*)d_in[2];
    const float* w2 = (const float*)d_in[3];
    const float* b2 = (const float*)d_in[4];
    const float* w3 = (const float*)d_in[5];
    const float* b3 = (const float*)d_in[6];
    const float* w4 = (const float*)d_in[7];
    const float* b4 = (const float*)d_in[8];
    const float* cb = (const float*)d_in[9];
    float* out = (float*)d_out;

    char* ws = (char*)d_ws;
    // z1 : 128MB @ 0            (conv1 out; dead after conv2)
    // z2 :  64MB @ 134217728   (conv2 out; dead after conv3p)
    // zp3:  64MB @ 0            (2 x 32MB partials; inside dead z1)
    // z3 :  32MB @ 67108864    (reduce3 out; dead after conv4p)
    // zp4:  64MB @ 0            (8 x 8MB partials; zp3 dead)
    // cbT:   8MB @ 67108864    (transpose, written after conv4p; z3 dead)
    // z4 :   8MB @ 134217728   (reduce4 out; z2 dead)
    // cn : 32KB @ 142606336 ; packed: 64KB @ 0 (zp4 dead once cnorm runs)
    float* z1  = (float*)(ws);
    float* z2  = (float*)(ws + 134217728);
    float* zp3 = (float*)(ws);
    float* z3  = (float*)(ws + 67108864);
    float* zp4 = (float*)(ws);
    float* cbt = (float*)(ws + 67108864);
    float* z4  = (float*)(ws + 134217728);
    float* cn  = (float*)(ws + 142606336);
    unsigned long long* pk = (unsigned long long*)(ws);

    // conv1: (32,3,256,256) -> (32,64,128,128)  old template, grid 4096
    conv_tiled_kernel<3, 3, 3, false, 48><<<32 * 1 * 16 * 8, THREADS, 0, stream>>>(
        x, w1, b1, z1, 32, 64, 256, 256, 1, 16, 8);
    // conv2: -> (32,128,64,64)  pipelined 128-co tile, grid 1024 = 4/CU exact
    conv_tiled8_kernel<64, 2, 64, false><<<32 * 1 * 8 * 4, THREADS, 0, stream>>>(
        z1, w2, b2, z2, 32, 128, 128, 128, 1, 8, 4);
    // conv3: -> partials (2 x 64ci), grid (512,2) = 1024
    conv_tiled8_kernel<64, 2, 128, true><<<dim3(32 * 2 * 4 * 2, 2), THREADS, 0, stream>>>(
        z2, w3, b3, zp3, 32, 256, 64, 64, 2, 4, 2);
    reduce_relu_kernel<2, 10><<<(32 * 256 * 32 * 32) / THREADS, THREADS, 0, stream>>>(
        zp3, b3, z3, 32 * 256 * 32 * 32);
    // conv4: -> partials (8 x 32ci), grid (128,8) = 1024
    conv_tiled8_kernel<32, 2, 256, true><<<dim3(32 * 2 * 2 * 1, 8), THREADS, 0, stream>>>(
        z3, w4, b4, zp4, 32, 256, 32, 32, 2, 2, 1);
    // z3 dead now -> transpose codebook into its region
    cbt_kernel<<<dim3(128, 4), THREADS, 0, stream>>>(cb, cbt);
    reduce_relu_kernel<8, 8><<<(32 * 256 * 16 * 16) / THREADS, THREADS, 0, stream>>>(
        zp4, b4, z4, 32 * 256 * 16 * 16);

    // VQ (cnorm fuses the packed-cell init)
    cnorm_kernel<<<8192 / THREADS, THREADS, 0, stream>>>(cb, cn, pk);
    vq_argmin_kernel<<<256 * 4, THREADS, 0, stream>>>(z4, cbt, cn, pk);

    // epilogue
    gather_kernel<<<(32 * 256 * 16 * 16) / THREADS, THREADS, 0, stream>>>(cb, pk, out);
}